// Round 3
// baseline (377.697 us; speedup 1.0000x reference)
//
#include <hip/hip_runtime.h>
#include <cstdint>
#include <cstddef>

// Problem constants: D delays, B batch, E pre, O post
#define DD 16
#define BB 8
#define EE 2048
#define OO 2048
#define NCH 256   // e-chunks (grid.y); 4 waves/block, 2 e's per wave -> 8*NCH = 2048 e's

// ---------------------------------------------------------------------------
// Kernel 1: pack coefficients C[e][d][b] = Xd[d,b,e] * (Wshort[d,b,e] + 1)
// and build per-e activity bitmask via atomicOr (mask pre-zeroed by memset).
// ---------------------------------------------------------------------------
__global__ void pack_coeffs(const float* __restrict__ Xd,
                            const float* __restrict__ Ws,
                            float* __restrict__ Cpack,
                            unsigned* __restrict__ mask) {
    int i = blockIdx.x * 256 + threadIdx.x;   // over D*B*E = 262144
    if (i >= DD * BB * EE) return;
    int e  = i & (EE - 1);
    int db = i >> 11;            // i / E
    int d  = db >> 3;            // db / B
    int b  = db & 7;             // db % B
    float x = Xd[i];
    float v = x * (Ws[i] + 1.0f);
    Cpack[((size_t)e * DD + d) * BB + b] = v;
    if (v != 0.0f) atomicOr(&mask[e], 1u << d);
}

__device__ __forceinline__ void fma4(float4& a, const float4& x, float s) {
    a.x = fmaf(x.x, s, a.x);
    a.y = fmaf(x.y, s, a.y);
    a.z = fmaf(x.z, s, a.z);
    a.w = fmaf(x.w, s, a.w);
}

// ---------------------------------------------------------------------------
// Main kernel.
// Grid: (8 o-tiles, NCH e-chunks). Block: 256 threads = 4 waves.
// Each wave owns TWO e's (e = ch*8 + wave*2 + ei); lane owns 4 consecutive
// o's. I[b,o] += (S*W)[e,o] * delaymap[d,e,o] * C[e][d][b] for d in mask[e].
// Deterministic: block-level LDS reduction -> per-chunk partial slices.
// ---------------------------------------------------------------------------
template <bool USE_PART>
__global__ __launch_bounds__(256, 6)
void synapse_main(const float* __restrict__ W,
                  const float* __restrict__ S,
                  const float* __restrict__ DM,
                  const float* __restrict__ Cpack,
                  const unsigned* __restrict__ mask,
                  float* __restrict__ Pout) {
    const int ot   = blockIdx.x;             // o-tile: 0..7
    const int ch   = blockIdx.y;             // e-chunk: 0..NCH-1
    const int wave = threadIdx.x >> 6;       // 0..3
    const int lane = threadIdx.x & 63;
    const int o0   = ot * 256 + lane * 4;

    float4 acc[BB];
#pragma unroll
    for (int b = 0; b < BB; ++b) acc[b] = make_float4(0.f, 0.f, 0.f, 0.f);

#pragma unroll
    for (int ei = 0; ei < 2; ++ei) {
        const int e = ch * 8 + wave * 2 + ei;

        float4 w4 = *reinterpret_cast<const float4*>(W + (size_t)e * OO + o0);
        float4 s4 = *reinterpret_cast<const float4*>(S + (size_t)e * OO + o0);
        float4 wf;
        wf.x = w4.x * s4.x; wf.y = w4.y * s4.y;
        wf.z = w4.z * s4.z; wf.w = w4.w * s4.w;

        unsigned m = mask[e];
        while (m) {
            const int d = __builtin_ctz(m);
            m &= (m - 1);
            const float4* cp = reinterpret_cast<const float4*>(
                Cpack + ((size_t)e * DD + d) * BB);
            float4 c0 = cp[0];
            float4 c1 = cp[1];
            float4 dm = *reinterpret_cast<const float4*>(
                DM + ((size_t)d * EE + e) * OO + o0);
            float4 dw;
            dw.x = dm.x * wf.x; dw.y = dm.y * wf.y;
            dw.z = dm.z * wf.z; dw.w = dm.w * wf.w;
            fma4(acc[0], dw, c0.x); fma4(acc[1], dw, c0.y);
            fma4(acc[2], dw, c0.z); fma4(acc[3], dw, c0.w);
            fma4(acc[4], dw, c1.x); fma4(acc[5], dw, c1.y);
            fma4(acc[6], dw, c1.z); fma4(acc[7], dw, c1.w);
        }
    }

    // Cross-wave reduction, two passes of 4 batches (16 KB LDS).
    __shared__ __align__(16) float red[4][4][256];
    const int t = threadIdx.x;
#pragma unroll
    for (int p = 0; p < 2; ++p) {
#pragma unroll
        for (int bb = 0; bb < 4; ++bb)
            *reinterpret_cast<float4*>(&red[wave][bb][lane * 4]) = acc[p * 4 + bb];
        __syncthreads();
        if (USE_PART) {
#pragma unroll
            for (int bb = 0; bb < 4; ++bb) {
                float s = red[0][bb][t] + red[1][bb][t] +
                          red[2][bb][t] + red[3][bb][t];
                Pout[((size_t)ch * BB + (p * 4 + bb)) * OO + ot * 256 + t] = s;
            }
        } else {
#pragma unroll
            for (int bb = 0; bb < 4; ++bb) {
                float s = red[0][bb][t] + red[1][bb][t] +
                          red[2][bb][t] + red[3][bb][t];
                atomicAdd(Pout + (size_t)(p * 4 + bb) * OO + ot * 256 + t, s);
            }
        }
        __syncthreads();
    }
}

// ---------------------------------------------------------------------------
// Kernel 3: reduce NCH partial slices -> out[b*O + o]
// ---------------------------------------------------------------------------
__global__ void reduce_partials(const float* __restrict__ P,
                                float* __restrict__ out) {
    int i = blockIdx.x * 256 + threadIdx.x;  // over B*O = 16384
    if (i >= BB * OO) return;
    int b = i >> 11;
    int o = i & (OO - 1);
    float s0 = 0.f, s1 = 0.f, s2 = 0.f, s3 = 0.f;
    const float* p = P + (size_t)b * OO + o;
#pragma unroll 4
    for (int ch = 0; ch < NCH; ch += 4) {
        s0 += p[(size_t)(ch + 0) * BB * OO];
        s1 += p[(size_t)(ch + 1) * BB * OO];
        s2 += p[(size_t)(ch + 2) * BB * OO];
        s3 += p[(size_t)(ch + 3) * BB * OO];
    }
    out[(size_t)b * OO + o] = (s0 + s1) + (s2 + s3);
}

// Fallback (no workspace): inline coefficients, atomicAdd output.
__global__ __launch_bounds__(256, 6)
void synapse_nows(const float* __restrict__ W,
                  const float* __restrict__ S,
                  const float* __restrict__ Xd,
                  const float* __restrict__ Ws,
                  const float* __restrict__ DM,
                  float* __restrict__ out) {
    const int ot   = blockIdx.x;
    const int ch   = blockIdx.y;
    const int wave = threadIdx.x >> 6;
    const int lane = threadIdx.x & 63;
    const int o0   = ot * 256 + lane * 4;

    float4 acc[BB];
#pragma unroll
    for (int b = 0; b < BB; ++b) acc[b] = make_float4(0.f, 0.f, 0.f, 0.f);

#pragma unroll
    for (int ei = 0; ei < 2; ++ei) {
        const int e = ch * 8 + wave * 2 + ei;

        float4 w4 = *reinterpret_cast<const float4*>(W + (size_t)e * OO + o0);
        float4 s4 = *reinterpret_cast<const float4*>(S + (size_t)e * OO + o0);
        float4 wf;
        wf.x = w4.x * s4.x; wf.y = w4.y * s4.y;
        wf.z = w4.z * s4.z; wf.w = w4.w * s4.w;

        for (int d = 0; d < DD; ++d) {
            float c[BB];
            bool nz = false;
#pragma unroll
            for (int b = 0; b < BB; ++b) {
                size_t idx = (size_t)(d * BB + b) * EE + e;
                float x = Xd[idx];
                c[b] = x * (Ws[idx] + 1.0f);
                nz |= (c[b] != 0.f);
            }
            if (!nz) continue;
            float4 dm = *reinterpret_cast<const float4*>(
                DM + ((size_t)d * EE + e) * OO + o0);
            float4 dw;
            dw.x = dm.x * wf.x; dw.y = dm.y * wf.y;
            dw.z = dm.z * wf.z; dw.w = dm.w * wf.w;
#pragma unroll
            for (int b = 0; b < BB; ++b) fma4(acc[b], dw, c[b]);
        }
    }

    __shared__ __align__(16) float red[4][4][256];
    const int t = threadIdx.x;
#pragma unroll
    for (int p = 0; p < 2; ++p) {
#pragma unroll
        for (int bb = 0; bb < 4; ++bb)
            *reinterpret_cast<float4*>(&red[wave][bb][lane * 4]) = acc[p * 4 + bb];
        __syncthreads();
#pragma unroll
        for (int bb = 0; bb < 4; ++bb) {
            float s = red[0][bb][t] + red[1][bb][t] +
                      red[2][bb][t] + red[3][bb][t];
            atomicAdd(out + (size_t)(p * 4 + bb) * OO + ot * 256 + t, s);
        }
        __syncthreads();
    }
}

extern "C" void kernel_launch(void* const* d_in, const int* in_sizes, int n_in,
                              void* d_out, int out_size, void* d_ws, size_t ws_size,
                              hipStream_t stream) {
    const float* W  = (const float*)d_in[0];
    const float* S  = (const float*)d_in[1];
    const float* Xd = (const float*)d_in[2];
    const float* Ws = (const float*)d_in[3];
    const float* DM = (const float*)d_in[4];
    float* out = (float*)d_out;

    const size_t packBytes = (size_t)EE * DD * BB * sizeof(float);     // 1 MiB
    const size_t maskBytes = (size_t)EE * sizeof(unsigned);            // 8 KiB
    const size_t partBytes = (size_t)NCH * BB * OO * sizeof(float);    // 16 MiB

    char* ws = (char*)d_ws;
    const bool canPack = ws_size >= packBytes + maskBytes;
    const bool canPart = ws_size >= packBytes + maskBytes + partBytes;

    dim3 grid(8, NCH), blk(256);

    if (canPack) {
        float*    Cp = (float*)ws;
        unsigned* mk = (unsigned*)(ws + packBytes);
        hipMemsetAsync(mk, 0, maskBytes, stream);
        pack_coeffs<<<(DD * BB * EE + 255) / 256, 256, 0, stream>>>(Xd, Ws, Cp, mk);
        if (canPart) {
            float* P = (float*)(ws + packBytes + maskBytes);
            synapse_main<true><<<grid, blk, 0, stream>>>(W, S, DM, Cp, mk, P);
            reduce_partials<<<(BB * OO + 255) / 256, 256, 0, stream>>>(P, out);
        } else {
            hipMemsetAsync(out, 0, (size_t)BB * OO * sizeof(float), stream);
            synapse_main<false><<<grid, blk, 0, stream>>>(W, S, DM, Cp, mk, out);
        }
    } else {
        hipMemsetAsync(out, 0, (size_t)BB * OO * sizeof(float), stream);
        synapse_nows<<<grid, blk, 0, stream>>>(W, S, Xd, Ws, DM, out);
    }
}

// Round 4
// 353.057 us; speedup vs baseline: 1.0698x; 1.0698x over previous
//
#include <hip/hip_runtime.h>
#include <cstdint>
#include <cstddef>

// Problem constants: D delays, B batch, E pre, O post
#define DD 16
#define BB 8
#define EE 2048
#define OO 2048
#define NCH 256   // e-chunks (grid.y); 4 waves/block, 2 e's per wave -> 8*NCH = 2048

// ---------------------------------------------------------------------------
// Kernel 1: pack coefficients C[e][d][b] = Xd[d,b,e] * (Wshort[d,b,e] + 1),
// build per-e activity bitmask via atomicOr (mask pre-zeroed by memset),
// and zero the output buffer (harness poisons it to 0xAA each iteration).
// ---------------------------------------------------------------------------
__global__ void pack_coeffs(const float* __restrict__ Xd,
                            const float* __restrict__ Ws,
                            float* __restrict__ Cpack,
                            unsigned* __restrict__ mask,
                            float* __restrict__ out) {
    int i = blockIdx.x * 256 + threadIdx.x;   // over D*B*E = 262144
    if (i < BB * OO) out[i] = 0.0f;           // first 64 blocks zero out[]
    if (i >= DD * BB * EE) return;
    int e  = i & (EE - 1);
    int db = i >> 11;            // i / E
    int d  = db >> 3;            // db / B
    int b  = db & 7;             // db % B
    float x = Xd[i];
    float v = x * (Ws[i] + 1.0f);
    Cpack[((size_t)e * DD + d) * BB + b] = v;
    if (v != 0.0f) atomicOr(&mask[e], 1u << d);
}

__device__ __forceinline__ void fma4(float4& a, const float4& x, float s) {
    a.x = fmaf(x.x, s, a.x);
    a.y = fmaf(x.y, s, a.y);
    a.z = fmaf(x.z, s, a.z);
    a.w = fmaf(x.w, s, a.w);
}

// ---------------------------------------------------------------------------
// Main kernel.
// Grid: (8 o-tiles, NCH e-chunks). Block: 256 threads = 4 waves.
// Each wave owns TWO e's, processed as INTERLEAVED streams so two
// independent (coeff + delaymap-row) load groups are in flight per
// iteration (the d-extraction loop otherwise serializes one ~700-cycle
// HBM latency per active delay). Lane owns 4 consecutive o's.
// Epilogue: LDS reduce across the 4 waves, then atomicAdd into out.
// ---------------------------------------------------------------------------
__global__ __launch_bounds__(256, 4)
void synapse_main(const float* __restrict__ W,
                  const float* __restrict__ S,
                  const float* __restrict__ DM,
                  const float* __restrict__ Cpack,
                  const unsigned* __restrict__ mask,
                  float* __restrict__ out) {
    const int ot   = blockIdx.x;             // o-tile: 0..7
    const int ch   = blockIdx.y;             // e-chunk: 0..NCH-1
    const int wave = threadIdx.x >> 6;       // 0..3
    const int lane = threadIdx.x & 63;
    const int o0   = ot * 256 + lane * 4;
    const int e0   = ch * 8 + wave * 2;
    const int e1   = e0 + 1;

    float4 acc[BB];
#pragma unroll
    for (int b = 0; b < BB; ++b) acc[b] = make_float4(0.f, 0.f, 0.f, 0.f);

    // Weff slices for both e's
    float4 w0 = *reinterpret_cast<const float4*>(W + (size_t)e0 * OO + o0);
    float4 s0 = *reinterpret_cast<const float4*>(S + (size_t)e0 * OO + o0);
    float4 w1 = *reinterpret_cast<const float4*>(W + (size_t)e1 * OO + o0);
    float4 s1 = *reinterpret_cast<const float4*>(S + (size_t)e1 * OO + o0);
    float4 wf0, wf1;
    wf0.x = w0.x * s0.x; wf0.y = w0.y * s0.y;
    wf0.z = w0.z * s0.z; wf0.w = w0.w * s0.w;
    wf1.x = w1.x * s1.x; wf1.y = w1.y * s1.y;
    wf1.z = w1.z * s1.z; wf1.w = w1.w * s1.w;

    unsigned m0 = mask[e0];
    unsigned m1 = mask[e1];

    while (m0 | m1) {
        const unsigned a0 = m0, a1 = m1;     // active flags (wave-uniform)
        float4 c00, c01, dm0;
        float4 c10, c11, dm1;
        // Issue BOTH streams' loads before either stream's FMAs.
        if (a0) {
            const int d = __builtin_ctz(m0);
            m0 &= (m0 - 1);
            const float4* cp = reinterpret_cast<const float4*>(
                Cpack + ((size_t)e0 * DD + d) * BB);
            c00 = cp[0];
            c01 = cp[1];
            dm0 = *reinterpret_cast<const float4*>(
                DM + ((size_t)d * EE + e0) * OO + o0);
        }
        if (a1) {
            const int d = __builtin_ctz(m1);
            m1 &= (m1 - 1);
            const float4* cp = reinterpret_cast<const float4*>(
                Cpack + ((size_t)e1 * DD + d) * BB);
            c10 = cp[0];
            c11 = cp[1];
            dm1 = *reinterpret_cast<const float4*>(
                DM + ((size_t)d * EE + e1) * OO + o0);
        }
        if (a0) {
            float4 dw;
            dw.x = dm0.x * wf0.x; dw.y = dm0.y * wf0.y;
            dw.z = dm0.z * wf0.z; dw.w = dm0.w * wf0.w;
            fma4(acc[0], dw, c00.x); fma4(acc[1], dw, c00.y);
            fma4(acc[2], dw, c00.z); fma4(acc[3], dw, c00.w);
            fma4(acc[4], dw, c01.x); fma4(acc[5], dw, c01.y);
            fma4(acc[6], dw, c01.z); fma4(acc[7], dw, c01.w);
        }
        if (a1) {
            float4 dw;
            dw.x = dm1.x * wf1.x; dw.y = dm1.y * wf1.y;
            dw.z = dm1.z * wf1.z; dw.w = dm1.w * wf1.w;
            fma4(acc[0], dw, c10.x); fma4(acc[1], dw, c10.y);
            fma4(acc[2], dw, c10.z); fma4(acc[3], dw, c10.w);
            fma4(acc[4], dw, c11.x); fma4(acc[5], dw, c11.y);
            fma4(acc[6], dw, c11.z); fma4(acc[7], dw, c11.w);
        }
    }

    // Cross-wave reduction, two passes of 4 batches (16 KB LDS),
    // then one atomicAdd per (thread, batch) into out.
    __shared__ __align__(16) float red[4][4][256];
    const int t = threadIdx.x;
#pragma unroll
    for (int p = 0; p < 2; ++p) {
#pragma unroll
        for (int bb = 0; bb < 4; ++bb)
            *reinterpret_cast<float4*>(&red[wave][bb][lane * 4]) = acc[p * 4 + bb];
        __syncthreads();
#pragma unroll
        for (int bb = 0; bb < 4; ++bb) {
            float s = red[0][bb][t] + red[1][bb][t] +
                      red[2][bb][t] + red[3][bb][t];
            atomicAdd(out + (size_t)(p * 4 + bb) * OO + ot * 256 + t, s);
        }
        __syncthreads();
    }
}

// Fallback (no workspace): inline coefficients, atomicAdd output.
__global__ __launch_bounds__(256, 4)
void synapse_nows(const float* __restrict__ W,
                  const float* __restrict__ S,
                  const float* __restrict__ Xd,
                  const float* __restrict__ Ws,
                  const float* __restrict__ DM,
                  float* __restrict__ out) {
    const int ot   = blockIdx.x;
    const int ch   = blockIdx.y;
    const int wave = threadIdx.x >> 6;
    const int lane = threadIdx.x & 63;
    const int o0   = ot * 256 + lane * 4;

    float4 acc[BB];
#pragma unroll
    for (int b = 0; b < BB; ++b) acc[b] = make_float4(0.f, 0.f, 0.f, 0.f);

#pragma unroll
    for (int ei = 0; ei < 2; ++ei) {
        const int e = ch * 8 + wave * 2 + ei;

        float4 w4 = *reinterpret_cast<const float4*>(W + (size_t)e * OO + o0);
        float4 s4 = *reinterpret_cast<const float4*>(S + (size_t)e * OO + o0);
        float4 wf;
        wf.x = w4.x * s4.x; wf.y = w4.y * s4.y;
        wf.z = w4.z * s4.z; wf.w = w4.w * s4.w;

        for (int d = 0; d < DD; ++d) {
            float c[BB];
            bool nz = false;
#pragma unroll
            for (int b = 0; b < BB; ++b) {
                size_t idx = (size_t)(d * BB + b) * EE + e;
                float x = Xd[idx];
                c[b] = x * (Ws[idx] + 1.0f);
                nz |= (c[b] != 0.f);
            }
            if (!nz) continue;
            float4 dm = *reinterpret_cast<const float4*>(
                DM + ((size_t)d * EE + e) * OO + o0);
            float4 dw;
            dw.x = dm.x * wf.x; dw.y = dm.y * wf.y;
            dw.z = dm.z * wf.z; dw.w = dm.w * wf.w;
#pragma unroll
            for (int b = 0; b < BB; ++b) fma4(acc[b], dw, c[b]);
        }
    }

    __shared__ __align__(16) float red[4][4][256];
    const int t = threadIdx.x;
#pragma unroll
    for (int p = 0; p < 2; ++p) {
#pragma unroll
        for (int bb = 0; bb < 4; ++bb)
            *reinterpret_cast<float4*>(&red[wave][bb][lane * 4]) = acc[p * 4 + bb];
        __syncthreads();
#pragma unroll
        for (int bb = 0; bb < 4; ++bb) {
            float s = red[0][bb][t] + red[1][bb][t] +
                      red[2][bb][t] + red[3][bb][t];
            atomicAdd(out + (size_t)(p * 4 + bb) * OO + ot * 256 + t, s);
        }
        __syncthreads();
    }
}

__global__ void zero_out(float* __restrict__ out) {
    int i = blockIdx.x * 256 + threadIdx.x;
    if (i < BB * OO) out[i] = 0.0f;
}

extern "C" void kernel_launch(void* const* d_in, const int* in_sizes, int n_in,
                              void* d_out, int out_size, void* d_ws, size_t ws_size,
                              hipStream_t stream) {
    const float* W  = (const float*)d_in[0];
    const float* S  = (const float*)d_in[1];
    const float* Xd = (const float*)d_in[2];
    const float* Ws = (const float*)d_in[3];
    const float* DM = (const float*)d_in[4];
    float* out = (float*)d_out;

    const size_t packBytes = (size_t)EE * DD * BB * sizeof(float);     // 1 MiB
    const size_t maskBytes = (size_t)EE * sizeof(unsigned);            // 8 KiB

    char* ws = (char*)d_ws;
    const bool canPack = ws_size >= packBytes + maskBytes;

    dim3 grid(8, NCH), blk(256);

    if (canPack) {
        float*    Cp = (float*)ws;
        unsigned* mk = (unsigned*)(ws + packBytes);
        hipMemsetAsync(mk, 0, maskBytes, stream);
        pack_coeffs<<<(DD * BB * EE + 255) / 256, 256, 0, stream>>>(Xd, Ws, Cp, mk, out);
        synapse_main<<<grid, blk, 0, stream>>>(W, S, DM, Cp, mk, out);
    } else {
        zero_out<<<(BB * OO + 255) / 256, 256, 0, stream>>>(out);
        synapse_nows<<<grid, blk, 0, stream>>>(W, S, Xd, Ws, DM, out);
    }
}

// Round 5
// 349.254 us; speedup vs baseline: 1.0814x; 1.0109x over previous
//
#include <hip/hip_runtime.h>
#include <cstdint>
#include <cstddef>

// Problem constants: D delays, B batch, E pre, O post
#define DD 16
#define BB 8
#define EE 2048
#define OO 2048
#define NCH 128   // e-chunks (grid.y); 4 waves/block, 4 e's per wave -> 16*NCH = 2048

// ---------------------------------------------------------------------------
// Kernel 1: pack coefficients C[e][d][b] = Xd[d,b,e] * (Wshort[d,b,e] + 1)
// (layout e*128 + d*8 + b) and zero the output buffer (harness poisons it).
// No mask pass: masks are derived in the main kernel via one ballot.
// ---------------------------------------------------------------------------
__global__ void pack_coeffs(const float* __restrict__ Xd,
                            const float* __restrict__ Ws,
                            float* __restrict__ Cpack,
                            float* __restrict__ out) {
    int i = blockIdx.x * 256 + threadIdx.x;   // over D*B*E = 262144
    if (i < BB * OO) out[i] = 0.0f;           // first 64 blocks zero out[]
    if (i >= DD * BB * EE) return;
    int e  = i & (EE - 1);
    int db = i >> 11;            // i / E
    int d  = db >> 3;            // db / B
    int b  = db & 7;             // db % B
    float x = Xd[i];
    Cpack[(size_t)e * (DD * BB) + d * BB + b] = x * (Ws[i] + 1.0f);
}

__device__ __forceinline__ void fma4(float4& a, const float4& x, float s) {
    a.x = fmaf(x.x, s, a.x);
    a.y = fmaf(x.y, s, a.y);
    a.z = fmaf(x.z, s, a.z);
    a.w = fmaf(x.w, s, a.w);
}

// ---------------------------------------------------------------------------
// Main kernel.
// Grid: (8 o-tiles, NCH e-chunks). Block: 256 threads = 4 waves.
// Each wave owns FOUR e's as interleaved streams (up to 4 independent
// delaymap-row loads in flight per loop iteration). Lane owns 4 consecutive
// o's. Delay masks come from ONE ballot: lane q*16+d tests C[e_q][d][*]!=0
// (coalesced 2KB read of Cpack); coefficients broadcast via __shfl of the
// same registers — no coefficient memory traffic in the loop.
// Epilogue: LDS reduce across the 4 waves, then atomicAdd into out.
// ---------------------------------------------------------------------------
__global__ __launch_bounds__(256, 4)
void synapse_main(const float* __restrict__ W,
                  const float* __restrict__ S,
                  const float* __restrict__ DM,
                  const float* __restrict__ Cpack,
                  float* __restrict__ out) {
    const int ot    = blockIdx.x;            // o-tile: 0..7
    const int ch    = blockIdx.y;            // e-chunk: 0..NCH-1
    const int wave  = threadIdx.x >> 6;      // 0..3
    const int lane  = threadIdx.x & 63;
    const int o0    = ot * 256 + lane * 4;
    const int ebase = ch * 16 + wave * 4;    // wave's 4 e's: ebase..ebase+3

    // --- ballot mask + coefficient row registers ---
    // lane = q*16 + d  ->  holds C[ebase+q][d][0..7]
    const int q_ln = lane >> 4;
    const int d_ln = lane & 15;
    const float4* crow = reinterpret_cast<const float4*>(
        Cpack + ((size_t)(ebase + q_ln) * (DD * BB)) + d_ln * BB);
    float4 ca = crow[0];
    float4 cb = crow[1];
    bool nz = (ca.x != 0.f) | (ca.y != 0.f) | (ca.z != 0.f) | (ca.w != 0.f) |
              (cb.x != 0.f) | (cb.y != 0.f) | (cb.z != 0.f) | (cb.w != 0.f);
    unsigned long long bal = __ballot(nz);
    unsigned m[4];
#pragma unroll
    for (int q = 0; q < 4; ++q) m[q] = (unsigned)(bal >> (16 * q)) & 0xFFFFu;

    // --- Weff slices for the 4 e's ---
    float4 wf[4];
#pragma unroll
    for (int q = 0; q < 4; ++q) {
        float4 w4 = *reinterpret_cast<const float4*>(W + (size_t)(ebase + q) * OO + o0);
        float4 s4 = *reinterpret_cast<const float4*>(S + (size_t)(ebase + q) * OO + o0);
        wf[q].x = w4.x * s4.x; wf[q].y = w4.y * s4.y;
        wf[q].z = w4.z * s4.z; wf[q].w = w4.w * s4.w;
    }

    float4 acc[BB];
#pragma unroll
    for (int b = 0; b < BB; ++b) acc[b] = make_float4(0.f, 0.f, 0.f, 0.f);

    while (m[0] | m[1] | m[2] | m[3]) {
        float4 dmv[4];
        int    dsrc[4];
        unsigned act = 0;
        // Issue all streams' delaymap-row loads before any FMAs.
#pragma unroll
        for (int q = 0; q < 4; ++q) {
            if (m[q]) {
                const int d = __builtin_ctz(m[q]);
                m[q] &= (m[q] - 1);
                dsrc[q] = q * 16 + d;        // source lane for coefficients
                dmv[q] = *reinterpret_cast<const float4*>(
                    DM + ((size_t)d * EE + (ebase + q)) * OO + o0);
                act |= 1u << q;
            }
        }
#pragma unroll
        for (int q = 0; q < 4; ++q) {
            if (act & (1u << q)) {
                const int sl = dsrc[q];
                float4 dw;
                dw.x = dmv[q].x * wf[q].x; dw.y = dmv[q].y * wf[q].y;
                dw.z = dmv[q].z * wf[q].z; dw.w = dmv[q].w * wf[q].w;
                fma4(acc[0], dw, __shfl(ca.x, sl));
                fma4(acc[1], dw, __shfl(ca.y, sl));
                fma4(acc[2], dw, __shfl(ca.z, sl));
                fma4(acc[3], dw, __shfl(ca.w, sl));
                fma4(acc[4], dw, __shfl(cb.x, sl));
                fma4(acc[5], dw, __shfl(cb.y, sl));
                fma4(acc[6], dw, __shfl(cb.z, sl));
                fma4(acc[7], dw, __shfl(cb.w, sl));
            }
        }
    }

    // Cross-wave reduction, two passes of 4 batches (16 KB LDS),
    // then one atomicAdd per (thread, batch) into out.
    __shared__ __align__(16) float red[4][4][256];
    const int t = threadIdx.x;
#pragma unroll
    for (int p = 0; p < 2; ++p) {
#pragma unroll
        for (int bb = 0; bb < 4; ++bb)
            *reinterpret_cast<float4*>(&red[wave][bb][lane * 4]) = acc[p * 4 + bb];
        __syncthreads();
#pragma unroll
        for (int bb = 0; bb < 4; ++bb) {
            float s = red[0][bb][t] + red[1][bb][t] +
                      red[2][bb][t] + red[3][bb][t];
            atomicAdd(out + (size_t)(p * 4 + bb) * OO + ot * 256 + t, s);
        }
        __syncthreads();
    }
}

// ---------------------------------------------------------------------------
// Fallback (no workspace): inline coefficients, atomicAdd output.
// ---------------------------------------------------------------------------
__global__ __launch_bounds__(256, 4)
void synapse_nows(const float* __restrict__ W,
                  const float* __restrict__ S,
                  const float* __restrict__ Xd,
                  const float* __restrict__ Ws,
                  const float* __restrict__ DM,
                  float* __restrict__ out) {
    const int ot    = blockIdx.x;
    const int ch    = blockIdx.y;
    const int wave  = threadIdx.x >> 6;
    const int lane  = threadIdx.x & 63;
    const int o0    = ot * 256 + lane * 4;
    const int ebase = ch * 16 + wave * 4;

    float4 acc[BB];
#pragma unroll
    for (int b = 0; b < BB; ++b) acc[b] = make_float4(0.f, 0.f, 0.f, 0.f);

    for (int ei = 0; ei < 4; ++ei) {
        const int e = ebase + ei;
        float4 w4 = *reinterpret_cast<const float4*>(W + (size_t)e * OO + o0);
        float4 s4 = *reinterpret_cast<const float4*>(S + (size_t)e * OO + o0);
        float4 wf;
        wf.x = w4.x * s4.x; wf.y = w4.y * s4.y;
        wf.z = w4.z * s4.z; wf.w = w4.w * s4.w;

        for (int d = 0; d < DD; ++d) {
            float c[BB];
            bool nz = false;
#pragma unroll
            for (int b = 0; b < BB; ++b) {
                size_t idx = (size_t)(d * BB + b) * EE + e;
                float x = Xd[idx];
                c[b] = x * (Ws[idx] + 1.0f);
                nz |= (c[b] != 0.f);
            }
            if (!nz) continue;
            float4 dm = *reinterpret_cast<const float4*>(
                DM + ((size_t)d * EE + e) * OO + o0);
            float4 dw;
            dw.x = dm.x * wf.x; dw.y = dm.y * wf.y;
            dw.z = dm.z * wf.z; dw.w = dm.w * wf.w;
#pragma unroll
            for (int b = 0; b < BB; ++b) fma4(acc[b], dw, c[b]);
        }
    }

    __shared__ __align__(16) float red[4][4][256];
    const int t = threadIdx.x;
#pragma unroll
    for (int p = 0; p < 2; ++p) {
#pragma unroll
        for (int bb = 0; bb < 4; ++bb)
            *reinterpret_cast<float4*>(&red[wave][bb][lane * 4]) = acc[p * 4 + bb];
        __syncthreads();
#pragma unroll
        for (int bb = 0; bb < 4; ++bb) {
            float s = red[0][bb][t] + red[1][bb][t] +
                      red[2][bb][t] + red[3][bb][t];
            atomicAdd(out + (size_t)(p * 4 + bb) * OO + ot * 256 + t, s);
        }
        __syncthreads();
    }
}

__global__ void zero_out(float* __restrict__ out) {
    int i = blockIdx.x * 256 + threadIdx.x;
    if (i < BB * OO) out[i] = 0.0f;
}

extern "C" void kernel_launch(void* const* d_in, const int* in_sizes, int n_in,
                              void* d_out, int out_size, void* d_ws, size_t ws_size,
                              hipStream_t stream) {
    const float* W  = (const float*)d_in[0];
    const float* S  = (const float*)d_in[1];
    const float* Xd = (const float*)d_in[2];
    const float* Ws = (const float*)d_in[3];
    const float* DM = (const float*)d_in[4];
    float* out = (float*)d_out;

    const size_t packBytes = (size_t)EE * DD * BB * sizeof(float);   // 1 MiB

    dim3 grid(8, NCH), blk(256);

    if (ws_size >= packBytes) {
        float* Cp = (float*)d_ws;
        pack_coeffs<<<(DD * BB * EE + 255) / 256, 256, 0, stream>>>(Xd, Ws, Cp, out);
        synapse_main<<<grid, blk, 0, stream>>>(W, S, DM, Cp, out);
    } else {
        zero_out<<<(BB * OO + 255) / 256, 256, 0, stream>>>(out);
        synapse_nows<<<grid, blk, 0, stream>>>(W, S, Xd, Ws, DM, out);
    }
}